// Round 6
// baseline (347.692 us; speedup 1.0000x reference)
//
#include <hip/hip_runtime.h>
#include <stdint.h>

// int8-quantized GEMM: out[m,n] = (sum_k x[m,k]*w[n,k]) * x_scale * w_scale, fp32 out.
// M=64, K=4096, N=14336. Inputs materialized as int32 -> weights are 235 MB.
//
// R2/R4: fragment-scattered global loads -> ~1.9 TB/s.
// R5: contiguous DMA staging + LDS fragment consume -> ~2.4 TB/s; binder was
//     8-way LDS bank conflicts (DMA forbids padding; every legal pitch gives a
//     multiple-of-4-bank fragment stride) + barrier-drain burstiness.
// R6 (this): two-pass. Pass 1 streams int32 at full BW, packs to int8 AND
//     reorders into MFMA-fragment order via an LDS transpose (swizzled, off the
//     HBM critical path). Pass 2 is a pure-stream gemm: contiguous fragment
//     loads straight to VGPRs + MFMA. No LDS, no barriers in the K-loop.
#define KDIM 4096
#define NDIM 14336
#define NTILES (NDIM / 16)        // 896 weight tiles (16 rows each)
#define TILE_OUT_BYTES 65536      // 64 chunks * 64 lanes * 16 B

typedef int v4i __attribute__((ext_vector_type(4)));

// pack4: low bytes of 4 sign-extended int32s -> one dword (4 int8s).
__device__ __forceinline__ int pack4(int w0, int w1, int w2, int w3) {
    int t01 = __builtin_amdgcn_perm(w1, w0, 0x00000400u);
    int t23 = __builtin_amdgcn_perm(w3, w2, 0x00000400u);
    return  __builtin_amdgcn_perm(t23, t01, 0x05040100u);
}

// Pass 1: one block per 16-row tile. Phase 1: stream tile (64K int32, fully
// lane-contiguous loads), pack to int8 into LDS [16 rows][4096 B] with a
// per-row rotate-by-4r swizzle (banks ~<=4-way both sides). Phase 2: emit the
// tile in MFMA-fragment order, fully lane-contiguous v4i stores.
// Fragment spec (HW-validated R2/R5): chunk c (K-span [c*64,c*64+64)),
// lane l: r=l&15 (row within tile), kg=l>>4, bytes = row[c*64 + kg*16 + j].
__global__ __launch_bounds__(256, 2) void pack_tile_kernel(
    const int* __restrict__ wq32,
    const int* __restrict__ xq32,
    int8_t* __restrict__ wf,
    int8_t* __restrict__ xf)
{
    __shared__ int8_t lds[16 * 4096];
    const int tid = threadIdx.x;
    const int T = blockIdx.x;

    const int* src;
    int8_t* dst;
    if (T < NTILES) {
        src = wq32 + (size_t)T * 16 * KDIM;
        dst = wf + (size_t)T * TILE_OUT_BYTES;
    } else {
        src = xq32 + (size_t)(T - NTILES) * 16 * KDIM;   // x m-tile (16 rows)
        dst = xf + (size_t)(T - NTILES) * TILE_OUT_BYTES;
    }

    // Phase 1: pack 16 rows. Row r, thread t, part p: int32s [p*1024+t*4, +4).
    #pragma unroll 4
    for (int r = 0; r < 16; ++r) {
        const int* rowp = src + r * KDIM;
        #pragma unroll
        for (int p = 0; p < 4; ++p) {
            const int idx = p * 1024 + tid * 4;          // int32 index == row byte
            v4i v = *(const v4i*)(rowp + idx);
            const int rb = (idx + r * 4) & 4095;         // rotate-by-4r swizzle
            *(int*)&lds[r * 4096 + rb] = pack4(v[0], v[1], v[2], v[3]);
        }
    }
    __syncthreads();

    // Phase 2: output v4i index o = i*256+tid -> chunk c=o>>6, lane l=o&63.
    #pragma unroll
    for (int i = 0; i < 16; ++i) {
        const int o = i * 256 + tid;
        const int c = o >> 6;
        const int l = o & 63;
        const int r = l & 15;
        const int kg = l >> 4;
        const int base = c * 64 + kg * 16;
        v4i d;
        #pragma unroll
        for (int e = 0; e < 4; ++e) {
            const int rb = (base + e * 4 + r * 4) & 4095;
            d[e] = *(const int*)&lds[r * 4096 + rb];
        }
        *(v4i*)(dst + (size_t)o * 16) = d;
    }
}

// Pass 2: pure-stream gemm. Block = 4 waves = one 16-wide N tile; wave w does
// m-tile w. Per chunk: contiguous B-frag load (wf, L3-hot), contiguous A-frag
// load (xf, L2-resident), MFMA. 64 chunks of K=64.
__global__ __launch_bounds__(256, 4) void gemm8_kernel(
    const int8_t* __restrict__ wf,
    const int8_t* __restrict__ xf,
    const float*  __restrict__ xs,
    const float*  __restrict__ wscale,
    float*        __restrict__ out)
{
    const int tid  = threadIdx.x;
    const int wave = tid >> 6;
    const int lane = tid & 63;
    const int r    = lane & 15;
    const int kg   = lane >> 4;

    const int8_t* wp = wf + (size_t)blockIdx.x * TILE_OUT_BYTES + lane * 16;
    const int8_t* ap = xf + (size_t)wave * TILE_OUT_BYTES + lane * 16;

    v4i acc = {0, 0, 0, 0};
    #pragma unroll 8
    for (int c = 0; c < 64; ++c) {
        v4i b = *(const v4i*)(wp + c * 1024);
        v4i a = *(const v4i*)(ap + c * 1024);
        acc = __builtin_amdgcn_mfma_i32_16x16x64_i8(a, b, acc, 0, 0, 0);
    }

    // Epilogue (HW-validated R2/R5): col = lane&15, row = (lane>>4)*4 + reg.
    const float scale = xs[0] * wscale[0];
    const int n = blockIdx.x * 16 + r;
    const int mbase = wave * 16 + kg * 4;
    #pragma unroll
    for (int i = 0; i < 4; ++i)
        out[(size_t)(mbase + i) * NDIM + n] = scale * (float)acc[i];
}

extern "C" void kernel_launch(void* const* d_in, const int* in_sizes, int n_in,
                              void* d_out, int out_size, void* d_ws, size_t ws_size,
                              hipStream_t stream) {
    const int*   xq32   = (const int*)d_in[0];
    const float* xs     = (const float*)d_in[1];
    const int*   wq32   = (const int*)d_in[2];
    const float* wscale = (const float*)d_in[3];
    float* out = (float*)d_out;

    // d_ws layout: xf (4 tiles, 256 KB) at 0; wf (896 tiles, 56 MB) at 1 MB.
    int8_t* xf = (int8_t*)d_ws;
    int8_t* wf = (int8_t*)d_ws + (1u << 20);

    pack_tile_kernel<<<NTILES + 4, 256, 0, stream>>>(wq32, xq32, wf, xf);
    gemm8_kernel<<<NTILES, 256, 0, stream>>>(wf, xf, xs, wscale, out);
}

// Round 7
// 322.418 us; speedup vs baseline: 1.0784x; 1.0784x over previous
//
#include <hip/hip_runtime.h>
#include <stdint.h>

// int8-quantized GEMM: out[m,n] = (sum_k x[m,k]*w[n,k]) * x_scale * w_scale, fp32 out.
// M=64, K=4096, N=14336. Inputs materialized as int32 -> weights are 235 MB.
// HBM floor ~37 us at 6.3 TB/s; harness adds ~220 us fixed re-poison per call.
//
// R2/R4: fragment-scattered global loads -> ~1.9 TB/s.
// R5: contiguous DMA staging + per-step FULL drain (vmcnt(0)+__syncthreads)
//     -> ~2.4 TB/s; budget math says LDS conflicts are sub-binder, the drain is.
// R6: two-pass regressed (extra 112 MB round trip).
// R7 (this): R5 staging/consume + 3-deep buffer ring, partial s_waitcnt vmcnt(4)
//     and RAW s_barrier (no compiler vmcnt(0) drain) -> one full step (16 KB/blk)
//     stays in flight across every barrier.
#define KDIM 4096
#define NDIM 14336
#define KSTEP 256                 // int32 per row per step (1 KB DMA per row)
#define NSTEPS (KDIM / KSTEP)     // 16
#define ROWB 1040                 // LDS row pitch (16B-aligned; DMA-proven in R5)
#define TILEB (16 * ROWB)         // one buffer = 16.25 KB; 3 bufs = 48.75 KB

typedef int v4i __attribute__((ext_vector_type(4)));

// pack4: low bytes of 4 sign-extended int32s -> one dword (4 int8s).
__device__ __forceinline__ int pack4(int w0, int w1, int w2, int w3) {
    int t01 = __builtin_amdgcn_perm(w1, w0, 0x00000400u);
    int t23 = __builtin_amdgcn_perm(w3, w2, 0x00000400u);
    return  __builtin_amdgcn_perm(t23, t01, 0x05040100u);
}

// Pre-kernel: pack x [64,4096] int32 -> int8 into d_ws (256 KB).
__global__ void pack_x_kernel(const int* __restrict__ xi, int* __restrict__ xo) {
    const int i = blockIdx.x * 256 + threadIdx.x;  // 65536 packed words
    v4i w = *(const v4i*)(xi + (size_t)i * 4);
    xo[i] = pack4(w[0], w[1], w[2], w[3]);
}

// Async 16B/lane global->LDS; dest = wave-uniform base + lane*16.
#define GLD_LDS(gptr, lptr) \
    __builtin_amdgcn_global_load_lds( \
        (const __attribute__((address_space(1))) int*)(const void*)(gptr), \
        (__attribute__((address_space(3))) int*)(void*)(lptr), 16, 0, 0)

// Block = 4 waves, one 16-wide N tile; wave w computes m-tile w against the
// shared 16-row weight tile. Each wave stages rows wave*4..wave*4+3 (1 KB
// contiguous DMA per row per step). 3 blocks/CU (48.75 KB LDS).
// Fragment spec (HW-validated R2/R5): row/col = lane&15, k = (lane>>4)*16 + j.
__global__ __launch_bounds__(256, 3) void gemm_i8_kernel(
    const int8_t* __restrict__ xp8,   // packed x (d_ws)
    const float*  __restrict__ xs,
    const int*    __restrict__ wq32,  // int32 weights
    const float*  __restrict__ wscale,
    float*        __restrict__ out)
{
    __shared__ int8_t lds[3 * TILEB];

    const int tid  = threadIdx.x;
    const int wave = tid >> 6;
    const int lane = tid & 63;
    const int r    = lane & 15;   // n within tile (B) / m within m-tile (A)
    const int kg   = lane >> 4;   // k-group 0..3
    const int n0   = blockIdx.x * 16;

    // Staging sources: wave stages rows wave*4+j; lane covers ints [lane*4,+4).
    const int* wsrc[4];
    #pragma unroll
    for (int j = 0; j < 4; ++j)
        wsrc[j] = wq32 + (size_t)(n0 + wave * 4 + j) * KDIM + lane * 4;

    // x fragment base for this wave's m-tile row (int8 indexing).
    const int8_t* xp = xp8 + (size_t)(wave * 16 + r) * KDIM + kg * 16;

    // LDS dest bases for this wave's 4 rows.
    int8_t* ldst[4];
    #pragma unroll
    for (int j = 0; j < 4; ++j)
        ldst[j] = lds + (wave * 4 + j) * ROWB;

    // ---- Prologue: queue = DMA(0)[4], x(0)[4], DMA(1)[4] ----
    #pragma unroll
    for (int j = 0; j < 4; ++j)
        GLD_LDS(wsrc[j], ldst[j] + 0 * TILEB);

    v4i ax[4];
    #pragma unroll
    for (int c = 0; c < 4; ++c)
        ax[c] = *(const v4i*)(xp + c * 64);

    #pragma unroll
    for (int j = 0; j < 4; ++j)
        GLD_LDS(wsrc[j] + KSTEP, ldst[j] + 1 * TILEB);

    v4i acc = {0, 0, 0, 0};

    #pragma unroll
    for (int s = 0; s < NSTEPS; ++s) {
        // Drain DMA(s) + x(s) (own-wave), leave DMA(s+1) in flight.
        if (s < NSTEPS - 1)
            asm volatile("s_waitcnt vmcnt(4)" ::: "memory");
        else
            asm volatile("s_waitcnt vmcnt(0)" ::: "memory");
        // RAW barrier: exec sync only. Every wave drained its OWN step-s rows
        // above -> after the barrier all 16 rows of step s are in LDS. Previous
        // step's ds_reads are data-dep drained (packs consumed them) before any
        // wave reaches this barrier -> WAR-safe to restage buf (s+2)%3 below.
        asm volatile("s_barrier" ::: "memory");

        // Prefetch x(s+1) BEFORE DMA(s+2): next iter's vmcnt(4) then covers it
        // without draining DMA(s+2).
        v4i axn[4];
        if (s + 1 < NSTEPS) {
            #pragma unroll
            for (int c = 0; c < 4; ++c)
                axn[c] = *(const v4i*)(xp + (s + 1) * KSTEP + c * 64);
        }
        if (s + 2 < NSTEPS) {
            #pragma unroll
            for (int j = 0; j < 4; ++j)
                GLD_LDS(wsrc[j] + (s + 2) * KSTEP, ldst[j] + ((s + 2) % 3) * TILEB);
        }

        // Consume buf s%3: 4 chunks of K=64; lane reads 16 int32 of row r,
        // packs to 16 int8, MFMA.
        const int8_t* lbase = lds + (s % 3) * TILEB + r * ROWB;
        #pragma unroll
        for (int c = 0; c < 4; ++c) {
            const v4i* p = (const v4i*)(lbase + c * 256 + kg * 64);
            v4i w0 = p[0], w1 = p[1], w2 = p[2], w3 = p[3];
            v4i b;
            b[0] = pack4(w0[0], w0[1], w0[2], w0[3]);
            b[1] = pack4(w1[0], w1[1], w1[2], w1[3]);
            b[2] = pack4(w2[0], w2[1], w2[2], w2[3]);
            b[3] = pack4(w3[0], w3[1], w3[2], w3[3]);
            acc = __builtin_amdgcn_mfma_i32_16x16x64_i8(ax[c], b, acc, 0, 0, 0);
        }

        if (s + 1 < NSTEPS) {
            #pragma unroll
            for (int c = 0; c < 4; ++c) ax[c] = axn[c];
        }
    }

    // Epilogue (HW-validated R2/R5): col = lane&15, row = (lane>>4)*4 + reg.
    const float scale = xs[0] * wscale[0];
    const int n = n0 + r;
    const int mbase = wave * 16 + kg * 4;
    #pragma unroll
    for (int i = 0; i < 4; ++i)
        out[(size_t)(mbase + i) * NDIM + n] = scale * (float)acc[i];
}

extern "C" void kernel_launch(void* const* d_in, const int* in_sizes, int n_in,
                              void* d_out, int out_size, void* d_ws, size_t ws_size,
                              hipStream_t stream) {
    const int*   xq32   = (const int*)d_in[0];
    const float* xs     = (const float*)d_in[1];
    const int*   wq32   = (const int*)d_in[2];
    const float* wscale = (const float*)d_in[3];
    float* out = (float*)d_out;

    int* x_packed = (int*)d_ws;  // 256 KB of d_ws

    pack_x_kernel<<<256, 256, 0, stream>>>(xq32, x_packed);

    const int nblocks = NDIM / 16;  // 896
    gemm_i8_kernel<<<nblocks, 256, 0, stream>>>((const int8_t*)x_packed, xs, wq32, wscale, out);
}

// Round 8
// 319.792 us; speedup vs baseline: 1.0872x; 1.0082x over previous
//
#include <hip/hip_runtime.h>
#include <stdint.h>

// int8-quantized GEMM: out[m,n] = (sum_k x[m,k]*w[n,k]) * x_scale * w_scale, fp32 out.
// M=64, K=4096, N=14336. Inputs materialized as int32 -> weights are 235 MB.
// HBM floor ~37 us; harness adds ~220 us fixed re-poison per timed call.
//
// R2/R4: fragment-scattered global loads -> ~1.9 TB/s.
// R5:    contiguous DMA staging, consume = 4 waves x full tile -> ~2.4 TB/s.
// R7:    pipelined ring (vmcnt(4) + raw barrier) -> NEUTRAL vs R5: consume-bound.
//        Binder arithmetic: 4x LDS-read amplification + 4x redundant pack VALU
//        + x-fragment 64-sector scatter stack to ~2.5x the DMA budget.
// R8 (this): consume split-K across waves (wave w eats chunk w only: LDS reads
//        and packs drop 4x), x pre-packed into fragment order (contiguous
//        A-loads), R2-validated cross-wave reduce epilogue. Staging ring kept.
#define KDIM 4096
#define NDIM 14336
#define KSTEP 256                 // int32 per row per step (1 KB DMA per row)
#define NSTEPS (KDIM / KSTEP)     // 16
#define ROWB 1040                 // LDS row pitch (DMA-proven in R5/R7)
#define TILEB (16 * ROWB)         // one buffer = 16.25 KB; 3 bufs = 48.75 KB
#define MT_BYTES 65536            // xf bytes per m-tile (64 chunks * 1 KB)

typedef int v4i __attribute__((ext_vector_type(4)));

// pack4: low bytes of 4 sign-extended int32s -> one dword (4 int8s).
__device__ __forceinline__ int pack4(int w0, int w1, int w2, int w3) {
    int t01 = __builtin_amdgcn_perm(w1, w0, 0x00000400u);
    int t23 = __builtin_amdgcn_perm(w3, w2, 0x00000400u);
    return  __builtin_amdgcn_perm(t23, t01, 0x05040100u);
}

// Pre-kernel: pack x [64,4096] int32 -> int8 in MFMA-FRAGMENT order:
// xf[mtile][chunk c][lane l][16 B] = x[mtile*16 + (l&15)][c*64 + (l>>4)*16 ..+16].
// 16384 output v4i; source is 1 MB (L2-absorbed; pattern cost irrelevant).
__global__ void pack_x_frag_kernel(const int* __restrict__ xi, int8_t* __restrict__ xf) {
    const int o   = blockIdx.x * 256 + threadIdx.x;  // 0..16383
    const int mt  = o >> 12;
    const int rem = o & 4095;
    const int c   = rem >> 6;
    const int l   = rem & 63;
    const int r   = l & 15;
    const int kg  = l >> 4;
    const int* src = xi + ((size_t)(mt * 16 + r) * KDIM + c * 64 + kg * 16);
    v4i d;
    #pragma unroll
    for (int e = 0; e < 4; ++e) {
        v4i v = *(const v4i*)(src + e * 4);
        d[e] = pack4(v[0], v[1], v[2], v[3]);
    }
    *(v4i*)(xf + (size_t)o * 16) = d;
}

// Async 16B/lane global->LDS; dest = wave-uniform base + lane*16.
#define GLD_LDS(gptr, lptr) \
    __builtin_amdgcn_global_load_lds( \
        (const __attribute__((address_space(1))) int*)(const void*)(gptr), \
        (__attribute__((address_space(3))) int*)(void*)(lptr), 16, 0, 0)

// Block = 4 waves, one 16-wide N tile. Staging: wave stages rows wave*4..+3
// (1 KB contiguous DMA per row per step). Consume: wave w packs/eats ONLY
// chunk w (K-span [s*256 + w*64, +64)) for all 4 m-tiles -> each staged dword
// read+packed once per block. Epilogue: cross-wave split-K reduce (R2-valid).
// Fragment spec (HW-validated R2/R5/R7): row/col = lane&15, k = (lane>>4)*16+j.
__global__ __launch_bounds__(256, 3) void gemm_i8_kernel(
    const int8_t* __restrict__ xf,    // fragment-ordered packed x (d_ws)
    const float*  __restrict__ xs,
    const int*    __restrict__ wq32,  // int32 weights
    const float*  __restrict__ wscale,
    float*        __restrict__ out)
{
    __shared__ int8_t lds[3 * TILEB];

    const int tid  = threadIdx.x;
    const int wave = tid >> 6;
    const int lane = tid & 63;
    const int r    = lane & 15;
    const int kg   = lane >> 4;
    const int n0   = blockIdx.x * 16;

    // Staging sources: wave stages rows wave*4+j; lane covers ints [lane*4,+4).
    const int* wsrc[4];
    #pragma unroll
    for (int j = 0; j < 4; ++j)
        wsrc[j] = wq32 + (size_t)(n0 + wave * 4 + j) * KDIM + lane * 4;

    int8_t* ldst[4];
    #pragma unroll
    for (int j = 0; j < 4; ++j)
        ldst[j] = lds + (wave * 4 + j) * ROWB;

    // A-source: wave w consumes global chunk s*4+w; contiguous 16 B per lane.
    const int8_t* ap = xf + lane * 16;

    // ---- Prologue: DMA(0)[4], x(0)[4], DMA(1)[4] ----
    #pragma unroll
    for (int j = 0; j < 4; ++j)
        GLD_LDS(wsrc[j], ldst[j] + 0 * TILEB);

    v4i ax[4];
    #pragma unroll
    for (int t = 0; t < 4; ++t)
        ax[t] = *(const v4i*)(ap + t * MT_BYTES + (size_t)(0 * 4 + wave) * 1024);

    #pragma unroll
    for (int j = 0; j < 4; ++j)
        GLD_LDS(wsrc[j] + KSTEP, ldst[j] + 1 * TILEB);

    v4i acc[4];
    #pragma unroll
    for (int t = 0; t < 4; ++t) acc[t] = (v4i){0, 0, 0, 0};

    #pragma unroll
    for (int s = 0; s < NSTEPS; ++s) {
        // Drain own DMA(s) + x(s); leave DMA(s+1) in flight (issued after x(s)).
        if (s < NSTEPS - 1)
            asm volatile("s_waitcnt vmcnt(4)" ::: "memory");
        else
            asm volatile("s_waitcnt vmcnt(0)" ::: "memory");
        // Raw exec barrier (no compiler vmcnt(0) drain). Each wave drained its
        // OWN step-s rows -> all 16 rows of step s visible. Step s-1 ds_reads
        // were data-dep drained before this point -> WAR-safe restage below.
        asm volatile("s_barrier" ::: "memory");

        // Prefetch x(s+1) BEFORE DMA(s+2) so next iter's vmcnt(4) covers it.
        v4i axn[4];
        if (s + 1 < NSTEPS) {
            #pragma unroll
            for (int t = 0; t < 4; ++t)
                axn[t] = *(const v4i*)(ap + t * MT_BYTES + (size_t)((s + 1) * 4 + wave) * 1024);
        }
        if (s + 2 < NSTEPS) {
            #pragma unroll
            for (int j = 0; j < 4; ++j)
                GLD_LDS(wsrc[j] + (s + 2) * KSTEP, ldst[j] + ((s + 2) % 3) * TILEB);
        }

        // Consume: wave w eats chunk w only. Lane (r,kg) reads 16 int32 of
        // row r at chunk-offset wave*256 + kg*64, packs to 16 int8, then 4
        // MFMAs (same B, 4 m-tile A's).
        const v4i* p = (const v4i*)(lds + (s % 3) * TILEB + r * ROWB + wave * 256 + kg * 64);
        v4i w0 = p[0], w1 = p[1], w2 = p[2], w3 = p[3];
        v4i b;
        b[0] = pack4(w0[0], w0[1], w0[2], w0[3]);
        b[1] = pack4(w1[0], w1[1], w1[2], w1[3]);
        b[2] = pack4(w2[0], w2[1], w2[2], w2[3]);
        b[3] = pack4(w3[0], w3[1], w3[2], w3[3]);

        acc[0] = __builtin_amdgcn_mfma_i32_16x16x64_i8(ax[0], b, acc[0], 0, 0, 0);
        acc[1] = __builtin_amdgcn_mfma_i32_16x16x64_i8(ax[1], b, acc[1], 0, 0, 0);
        acc[2] = __builtin_amdgcn_mfma_i32_16x16x64_i8(ax[2], b, acc[2], 0, 0, 0);
        acc[3] = __builtin_amdgcn_mfma_i32_16x16x64_i8(ax[3], b, acc[3], 0, 0, 0);

        if (s + 1 < NSTEPS) {
            #pragma unroll
            for (int t = 0; t < 4; ++t) ax[t] = axn[t];
        }
    }

    // Wait for ALL waves to finish consuming the last buffer before aliasing
    // the staging LDS as the reduction scratch (last buf index 15%3 == 0).
    __syncthreads();

    // Split-K reduction (R2-validated): red[src_wave][m_tile][lane*4+i].
    int (*red)[4][256] = (int (*)[4][256])&lds[0];
    ((v4i*)red[wave][0])[lane] = acc[0];
    ((v4i*)red[wave][1])[lane] = acc[1];
    ((v4i*)red[wave][2])[lane] = acc[2];
    ((v4i*)red[wave][3])[lane] = acc[3];
    __syncthreads();

    v4i s0 = ((v4i*)red[0][wave])[lane];
    v4i s1 = ((v4i*)red[1][wave])[lane];
    v4i s2 = ((v4i*)red[2][wave])[lane];
    v4i s3 = ((v4i*)red[3][wave])[lane];
    v4i tot = s0 + s1 + s2 + s3;

    // C/D layout (HW-validated R2): col = lane&15, row = (lane>>4)*4 + reg.
    const float scale = xs[0] * wscale[0];
    const int n = n0 + r;
    const int mbase = wave * 16 + kg * 4;
    #pragma unroll
    for (int i = 0; i < 4; ++i)
        out[(size_t)(mbase + i) * NDIM + n] = scale * (float)tot[i];
}

extern "C" void kernel_launch(void* const* d_in, const int* in_sizes, int n_in,
                              void* d_out, int out_size, void* d_ws, size_t ws_size,
                              hipStream_t stream) {
    const int*   xq32   = (const int*)d_in[0];
    const float* xs     = (const float*)d_in[1];
    const int*   wq32   = (const int*)d_in[2];
    const float* wscale = (const float*)d_in[3];
    float* out = (float*)d_out;

    int8_t* xf = (int8_t*)d_ws;  // 256 KB fragment-ordered packed x

    pack_x_frag_kernel<<<64, 256, 0, stream>>>(xq32, xf);

    const int nblocks = NDIM / 16;  // 896
    gemm_i8_kernel<<<nblocks, 256, 0, stream>>>(xf, xs, wq32, wscale, out);
}